// Round 7
// baseline (319.510 us; speedup 1.0000x reference)
//
#include <hip/hip_runtime.h>

// B=4, H=8, L=1024, D=64, QDIM=512.
#define QD 512
#define NW (512*512)  // elements per weight matrix

typedef __attribute__((ext_vector_type(8))) short bf16x8;  // 8 bf16
typedef __attribute__((ext_vector_type(4))) short bf16x4;  // 4 bf16
typedef __attribute__((ext_vector_type(4))) float f32x4;

#define MFMA16(a,b,c) __builtin_amdgcn_mfma_f32_16x16x32_bf16((a),(b),(c),0,0,0)

static __device__ __forceinline__ short f2bf(float f) {  // RNE float->bf16
  unsigned u = __float_as_uint(f);
  u += 0x7fffu + ((u >> 16) & 1u);
  return (short)(u >> 16);
}
static __device__ __forceinline__ float bf2f(short s) {
  return __uint_as_float(((unsigned)(unsigned short)s) << 16);
}
static __device__ __forceinline__ unsigned pk2(float a, float b) {
  return (unsigned)(unsigned short)f2bf(a) | (((unsigned)(unsigned short)f2bf(b)) << 16);
}

#define GL2LDS16(g, l)                                                        \
  __builtin_amdgcn_global_load_lds(                                           \
      (const __attribute__((address_space(1))) unsigned int*)(g),             \
      (__attribute__((address_space(3))) unsigned int*)(l), 16, 0, 0)

// ---------------- K0: weights -> bf16 (hi/lo for wq,wk,wp; hi for wv) -------
__global__ __launch_bounds__(256) void k_wconv(
    const float* __restrict__ wq, const float* __restrict__ wk,
    const float* __restrict__ wv, const float* __restrict__ wp,
    short* __restrict__ W, short* __restrict__ WPH, short* __restrict__ WPL) {
  int i = blockIdx.x * 256 + threadIdx.x;
  if (i < NW) {
    float f = wq[i]; short h = f2bf(f);
    W[i] = h; W[NW + i] = f2bf(f - bf2f(h));
  } else if (i < 2 * NW) {
    int j = i - NW;
    float f = wk[j]; short h = f2bf(f);
    W[2 * NW + j] = h; W[3 * NW + j] = f2bf(f - bf2f(h));
  } else if (i < 3 * NW) {
    int j = i - 2 * NW;
    W[4 * NW + j] = f2bf(wv[j]);
  } else {
    int j = i - 3 * NW;
    if (j < 64 * QD) {
      float f = wp[j]; short h = f2bf(f);
      WPH[j] = h; WPL[j] = f2bf(f - bf2f(h));
    }
  }
}

// ---------------- K0b: activations -> bf16 (hi/lo for q,k; hi for v) --------
__global__ __launch_bounds__(256) void k_xconv(
    const float* __restrict__ q, const float* __restrict__ k, const float* __restrict__ v,
    short* __restrict__ XqH, short* __restrict__ XqL,
    short* __restrict__ XkH, short* __restrict__ XkL, short* __restrict__ XvH) {
  int i = blockIdx.x * 256 + threadIdx.x;   // one group of 8 floats
  int t = i >> 18;
  int j = i & 0x3FFFF;
  const float* src = t == 0 ? q : (t == 1 ? k : v);
  f32x4 x0 = *(const f32x4*)(src + (size_t)j * 8);
  f32x4 x1 = *(const f32x4*)(src + (size_t)j * 8 + 4);
  bf16x8 H, L;
#pragma unroll
  for (int jj = 0; jj < 4; ++jj) {
    short h0 = f2bf(x0[jj]); H[jj] = h0; L[jj] = f2bf(x0[jj] - bf2f(h0));
    short h1 = f2bf(x1[jj]); H[jj + 4] = h1; L[jj + 4] = f2bf(x1[jj] - bf2f(h1));
  }
  if (t == 0)      { *(bf16x8*)(XqH + (size_t)j * 8) = H; *(bf16x8*)(XqL + (size_t)j * 8) = L; }
  else if (t == 1) { *(bf16x8*)(XkH + (size_t)j * 8) = H; *(bf16x8*)(XkL + (size_t)j * 8) = L; }
  else             { *(bf16x8*)(XvH + (size_t)j * 8) = H; }
}

// ---------------- K1: projection GEMM, LDS-staged, split-bf16 ---------------
// C(4096x512) = (X @ W^T + bias) * scale. mode 0: hi/lo -> [b,h,l,d];
// mode 1 (V): bf16 -> [b,h,d,l].
__global__ __launch_bounds__(256) void k_proj(
    const short* __restrict__ XH, const short* __restrict__ XL,
    const short* __restrict__ WH, const short* __restrict__ WL,
    const float* __restrict__ bias,
    short* __restrict__ outH, short* __restrict__ outL,
    short* __restrict__ Vt, int mode, float scale) {
  __shared__ __align__(16) short Ah[64 * 32], Al[64 * 32], Bh[64 * 32], Bl[64 * 32];
  const int tid = threadIdx.x;
  const int lane = tid & 63;
  const int col = lane & 15, g = lane >> 4;
  const int w = tid >> 6, wr = w >> 1, wc = w & 1;
  const int h = blockIdx.x;
  const int m0 = blockIdx.y * 64;
  const int srow = tid >> 2;
  const int scol = ((tid & 3) ^ (srow & 3)) * 8;
  const size_t xrow = (size_t)(m0 + srow) * QD + scol;
  const size_t wrow = (size_t)(h * 64 + srow) * QD + scol;

  f32x4 zero = {0.f, 0.f, 0.f, 0.f};
  f32x4 acc[2][2] = {{zero, zero}, {zero, zero}};

  for (int kc = 0; kc < 16; ++kc) {
    const int kb = kc * 32;
    GL2LDS16(XH + xrow + kb, &Ah[tid * 8]);
    GL2LDS16(WH + wrow + kb, &Bh[tid * 8]);
    if (mode == 0) {
      GL2LDS16(XL + xrow + kb, &Al[tid * 8]);
      GL2LDS16(WL + wrow + kb, &Bl[tid * 8]);
    }
    __syncthreads();

    bf16x8 a_h[2], a_l[2], b_h[2], b_l[2];
#pragma unroll
    for (int mt = 0; mt < 2; ++mt) {
      int rowa = wr * 32 + mt * 16 + col;
      int off = rowa * 32 + ((g ^ (rowa & 3)) * 8);
      a_h[mt] = *(const bf16x8*)&Ah[off];
      if (mode == 0) a_l[mt] = *(const bf16x8*)&Al[off];
    }
#pragma unroll
    for (int nt = 0; nt < 2; ++nt) {
      int rowb = wc * 32 + nt * 16 + col;
      int off = rowb * 32 + ((g ^ (rowb & 3)) * 8);
      b_h[nt] = *(const bf16x8*)&Bh[off];
      if (mode == 0) b_l[nt] = *(const bf16x8*)&Bl[off];
    }
#pragma unroll
    for (int mt = 0; mt < 2; ++mt)
#pragma unroll
      for (int nt = 0; nt < 2; ++nt) {
        acc[mt][nt] = MFMA16(a_h[mt], b_h[nt], acc[mt][nt]);
        if (mode == 0) {
          acc[mt][nt] = MFMA16(a_l[mt], b_h[nt], acc[mt][nt]);
          acc[mt][nt] = MFMA16(a_h[mt], b_l[nt], acc[mt][nt]);
        }
      }
    __syncthreads();
  }

#pragma unroll
  for (int nt = 0; nt < 2; ++nt) {
    int d = wc * 32 + nt * 16 + col;
    float bias_v = bias[h * 64 + d];
#pragma unroll
    for (int mt = 0; mt < 2; ++mt)
#pragma unroll
      for (int r = 0; r < 4; ++r) {
        int m = m0 + wr * 32 + mt * 16 + g * 4 + r;
        int b = m >> 10, l = m & 1023;
        float val = (acc[mt][nt][r] + bias_v) * scale;
        if (mode == 0) {
          size_t idx = (((size_t)b * 8 + h) * 1024 + l) * 64 + d;
          short hh = f2bf(val);
          outH[idx] = hh;
          outL[idx] = f2bf(val - bf2f(hh));
        } else {
          Vt[(((size_t)b * 8 + h) * 64 + d) * 1024 + l] = f2bf(val);
        }
      }
  }
}

// ---------------- K2: partial row sums of exp(S), k-split x4 ----------------
// mfma(K,Q): D[row=k][col=q]; block (qblk,bh,kq) handles 64 q x 256 k and
// atomicAdds its partial sums. Q carries the 0.5 scale (folded in k_proj).
__global__ __launch_bounds__(256) void k_sums(
    const short* __restrict__ QsH, const short* __restrict__ KsH,
    float* __restrict__ sums) {
  __shared__ __align__(16) short KL[32 * 64];  // 32 k-rows x 64 d
  const int tid = threadIdx.x;
  const int lane = tid & 63, w = tid >> 6;
  const int col = lane & 15, g = lane >> 4;
  int wgid = blockIdx.x + gridDim.x * blockIdx.y;     // XCD-aware swizzle
  int nid = (wgid & 7) * 64 + (wgid >> 3);
  const int qblk = nid & 15, bh = nid >> 4;
  const int kq = blockIdx.z;                          // k-quarter
  const int q0 = qblk * 64 + w * 16;
  const size_t base = (size_t)bh * 65536;

  const short* qp = QsH + base + (size_t)(q0 + col) * 64 + g * 8;
  bf16x8 qB0 = *(const bf16x8*)qp;
  bf16x8 qB1 = *(const bf16x8*)(qp + 32);

  const int srow = tid >> 3, sslot = tid & 7;
  const short* ksrc = KsH + base + (size_t)(kq * 256 + srow) * 64 +
                      ((sslot ^ (srow & 7)) * 8);

  f32x4 zero = {0.f, 0.f, 0.f, 0.f};
  float sum = 0.f;
  for (int kb = 0; kb < 8; ++kb) {
    GL2LDS16(ksrc + kb * 2048, &KL[tid * 8]);
    __syncthreads();
#pragma unroll
    for (int sub = 0; sub < 2; ++sub) {
      const short* lb = &KL[(sub * 16 + col) * 64];
      bf16x8 ka0 = *(const bf16x8*)(lb + ((g ^ (col & 7)) * 8));
      bf16x8 ka1 = *(const bf16x8*)(lb + (((4 + g) ^ (col & 7)) * 8));
      f32x4 S = zero;
      S = MFMA16(ka0, qB0, S);
      S = MFMA16(ka1, qB1, S);
      sum += __expf(S[0]) + __expf(S[1]) + __expf(S[2]) + __expf(S[3]);
    }
    __syncthreads();
  }
  sum += __shfl_xor(sum, 16);
  sum += __shfl_xor(sum, 32);
  if (lane < 16) atomicAdd(&sums[bh * 1024 + q0 + col], sum);
}

// ---------------- K2b: invert sums in place ---------------------------------
__global__ __launch_bounds__(256) void k_inv(float* __restrict__ s) {
  int i = blockIdx.x * 256 + threadIdx.x;
  s[i] = 1.f / s[i];
}

// ---------------- K3: fused attn write + partial context, q-split -----------
// mfma(Q,K): D[row=q][col=k]; P's lane layout = the PV A-frag directly.
// Block (kblk,bh,qc) covers 64 k x (cpb*32) q; fp32 partial ctx per chunk.
__global__ __launch_bounds__(256) void k_pv(
    const short* __restrict__ QsH, const short* __restrict__ QsL,
    const short* __restrict__ KsH, const short* __restrict__ KsL,
    const short* __restrict__ Vt, const float* __restrict__ invp,
    float* __restrict__ attn,
    float* __restrict__ c0, float* __restrict__ c1,
    float* __restrict__ c2, float* __restrict__ c3, int cpb) {
  __shared__ __align__(16) short QH[32 * 64], QL[32 * 64];  // 4 KB each
  const int tid = threadIdx.x;
  const int lane = tid & 63, w = tid >> 6;
  const int col = lane & 15, g = lane >> 4;
  int wgid = blockIdx.x + gridDim.x * blockIdx.y;     // XCD-aware swizzle
  int nid = (wgid & 7) * 64 + (wgid >> 3);
  const int kblk = nid & 15, bh = nid >> 4;
  const int qc = blockIdx.z;
  float* ctxP = qc == 0 ? c0 : (qc == 1 ? c1 : (qc == 2 ? c2 : c3));
  const int k0 = kblk * 64 + w * 16;
  const size_t base = (size_t)bh * 65536;

  // K fragments (B-operand), fixed for the whole kernel: rows k0+col.
  const short* kp = KsH + base + (size_t)(k0 + col) * 64 + g * 8;
  bf16x8 khB0 = *(const bf16x8*)kp;
  bf16x8 khB1 = *(const bf16x8*)(kp + 32);
  const short* kpl = KsL + base + (size_t)(k0 + col) * 64 + g * 8;
  bf16x8 klB0 = *(const bf16x8*)kpl;
  bf16x8 klB1 = *(const bf16x8*)(kpl + 32);

  const short* vb = Vt + base;                     // [64][1024]
  float* ab = attn + (size_t)bh * 1024 * 1024;
  const float* invB = invp + bh * 1024;

  const int srow = tid >> 3, sslot = tid & 7;
  const size_t qsrc = base + (size_t)srow * 64 + ((sslot ^ (srow & 7)) * 8);

  f32x4 zero = {0.f, 0.f, 0.f, 0.f};
  f32x4 O[4] = {zero, zero, zero, zero};

  for (int ci = 0; ci < cpb; ++ci) {
    const int cc = qc * cpb + ci;
    GL2LDS16(QsH + qsrc + cc * 2048, &QH[tid * 8]);
    GL2LDS16(QsL + qsrc + cc * 2048, &QL[tid * 8]);
    __syncthreads();

    float p[2][4];
#pragma unroll
    for (int t = 0; t < 2; ++t) {
      const short* lh = &QH[(t * 16 + col) * 64];
      const short* ll = &QL[(t * 16 + col) * 64];
      int o0 = (g ^ (col & 7)) * 8, o1 = ((4 + g) ^ (col & 7)) * 8;
      bf16x8 qh0 = *(const bf16x8*)(lh + o0);
      bf16x8 qh1 = *(const bf16x8*)(lh + o1);
      bf16x8 ql0 = *(const bf16x8*)(ll + o0);
      bf16x8 ql1 = *(const bf16x8*)(ll + o1);
      f32x4 S = zero;
      S = MFMA16(qh0, khB0, S);
      S = MFMA16(qh1, khB1, S);
      S = MFMA16(ql0, khB0, S);
      S = MFMA16(ql1, khB1, S);
      S = MFMA16(qh0, klB0, S);
      S = MFMA16(qh1, klB1, S);
      f32x4 iv = *(const f32x4*)(invB + cc * 32 + t * 16 + 4 * g);
      float* ap = ab + (size_t)(cc * 32 + t * 16 + 4 * g) * 1024 + k0 + col;
#pragma unroll
      for (int r = 0; r < 4; ++r) {
        p[t][r] = __expf(S[r]) * iv[r];
        ap[(size_t)r * 1024] = p[t][r];
      }
    }
    // Pack P as the PV A-fragment; read V in the same q-permutation.
    union { bf16x8 v; unsigned u[4]; } pa;
    pa.u[0] = pk2(p[0][0], p[0][1]); pa.u[1] = pk2(p[0][2], p[0][3]);
    pa.u[2] = pk2(p[1][0], p[1][1]); pa.u[3] = pk2(p[1][2], p[1][3]);
#pragma unroll
    for (int dt = 0; dt < 4; ++dt) {
      const short* vr = vb + (size_t)(dt * 16 + col) * 1024 + cc * 32 + 4 * g;
      union { bf16x8 v; bf16x4 h[2]; } vf;
      vf.h[0] = *(const bf16x4*)vr;
      vf.h[1] = *(const bf16x4*)(vr + 16);
      O[dt] = MFMA16(pa.v, vf.v, O[dt]);
    }
    __syncthreads();
  }

  int b = bh >> 3, h = bh & 7;
#pragma unroll
  for (int dt = 0; dt < 4; ++dt)
#pragma unroll
    for (int r = 0; r < 4; ++r) {
      int kk = k0 + 4 * g + r;
      ctxP[((size_t)(b * 1024 + kk)) * 512 + h * 64 + dt * 16 + col] = O[dt][r];
    }
}

// ---------------- K3b: reduce partial ctx -> hi/lo bf16 ---------------------
__global__ __launch_bounds__(256) void k_red(
    const float* __restrict__ c0, const float* __restrict__ c1,
    const float* __restrict__ c2, const float* __restrict__ c3, int nc,
    short* __restrict__ ctxH, short* __restrict__ ctxL) {
  size_t i = ((size_t)blockIdx.x * 256 + threadIdx.x) * 8;
  f32x4 a0 = *(const f32x4*)(c0 + i);
  f32x4 a1 = *(const f32x4*)(c0 + i + 4);
  if (nc > 1) { a0 += *(const f32x4*)(c1 + i); a1 += *(const f32x4*)(c1 + i + 4); }
  if (nc > 2) { a0 += *(const f32x4*)(c2 + i); a1 += *(const f32x4*)(c2 + i + 4);
                a0 += *(const f32x4*)(c3 + i); a1 += *(const f32x4*)(c3 + i + 4); }
  bf16x8 H, L;
#pragma unroll
  for (int j = 0; j < 4; ++j) {
    short h0 = f2bf(a0[j]); H[j] = h0; L[j] = f2bf(a0[j] - bf2f(h0));
    short h1 = f2bf(a1[j]); H[j + 4] = h1; L[j + 4] = f2bf(a1[j] - bf2f(h1));
  }
  *(bf16x8*)(ctxH + i) = H;
  *(bf16x8*)(ctxL + i) = L;
}

// ---------------- K4: output = ctx @ wp^T + bp (3-term split) ---------------
__global__ __launch_bounds__(256) void k_out(
    const short* __restrict__ ctxH, const short* __restrict__ ctxL,
    const short* __restrict__ WPH, const short* __restrict__ WPL,
    const float* __restrict__ bp, float* __restrict__ out) {
  const int lane = threadIdx.x & 63, w = threadIdx.x >> 6;
  const int col = lane & 15, g = lane >> 4;
  const int m0 = blockIdx.x * 64 + w * 16;

  f32x4 zero = {0.f, 0.f, 0.f, 0.f};
  f32x4 acc[4] = {zero, zero, zero, zero};

  for (int kc = 0; kc < 16; ++kc) {
    size_t aoff = (size_t)(m0 + col) * 512 + kc * 32 + g * 8;
    bf16x8 a_h = *(const bf16x8*)(ctxH + aoff);
    bf16x8 a_l = *(const bf16x8*)(ctxL + aoff);
#pragma unroll
    for (int nt = 0; nt < 4; ++nt) {
      size_t boff = (size_t)(nt * 16 + col) * 512 + kc * 32 + g * 8;
      bf16x8 b_h = *(const bf16x8*)(WPH + boff);
      bf16x8 b_l = *(const bf16x8*)(WPL + boff);
      acc[nt] = MFMA16(a_h, b_h, acc[nt]);
      acc[nt] = MFMA16(a_l, b_h, acc[nt]);
      acc[nt] = MFMA16(a_h, b_l, acc[nt]);
    }
  }
#pragma unroll
  for (int nt = 0; nt < 4; ++nt) {
    float bias = bp[nt * 16 + col];
#pragma unroll
    for (int r = 0; r < 4; ++r)
      out[(size_t)(m0 + g * 4 + r) * 64 + nt * 16 + col] = acc[nt][r] + bias;
  }
}

extern "C" void kernel_launch(void* const* d_in, const int* in_sizes, int n_in,
                              void* d_out, int out_size, void* d_ws, size_t ws_size,
                              hipStream_t stream) {
  const float* q  = (const float*)d_in[0];
  const float* k  = (const float*)d_in[1];
  const float* v  = (const float*)d_in[2];
  const float* wq = (const float*)d_in[3];
  const float* bq = (const float*)d_in[4];
  const float* wk = (const float*)d_in[5];
  const float* bk = (const float*)d_in[6];
  const float* wv = (const float*)d_in[7];
  const float* bv = (const float*)d_in[8];
  const float* wp = (const float*)d_in[9];
  const float* bp = (const float*)d_in[10];

  float* out  = (float*)d_out;            // (4,1024,64)
  float* attn = out + 262144;             // (4,8,1024,1024)

  // workspace layout (E = 2M shorts = 4 MB), live-range aliased:
  short* S = (short*)d_ws;
  const size_t E = 2097152;
  short* XqH = S;                         // -> KsH (k_pv) -> ctxH (k_red/k_out)
  short* XqL = S + E;                     // -> KsL        -> ctxL
  short* XkH = S + 2 * E;                 // -> Vt
  short* XkL = S + 3 * E;                 // -> ctxP0 (fp32, spans 3E..5E)
  short* XvH = S + 4 * E;
  short* QsH = S + 5 * E;
  short* QsL = S + 6 * E;
  short* KsH = S;
  short* KsL = S + E;
  short* Vt  = S + 2 * E;
  short* ctxH = S;
  short* ctxL = S + E;
  short* W   = S + 7 * E;                 // [WqH|WqL|WkH|WkL|WvH]
  short* WPH = W + 5 * (size_t)NW;        // [64][512]
  short* WPL = WPH + 64 * QD;
  float* sums = (float*)(WPL + 64 * QD);  // [32][1024] f32 (128 KB)
  float* ctxP0 = (float*)(S + 3 * E);     // 8 MB fp32 partial (base region)
  char*  tail = (char*)(sums + 32768);
  size_t used = (size_t)(tail - (char*)d_ws);
  size_t avail = ws_size > used ? ws_size - used : 0;
  const size_t CB = (size_t)8 * 1024 * 1024;    // bytes per partial-ctx buffer
  int NC = avail >= 3 * CB ? 4 : (avail >= CB ? 2 : 1);
  float* c1 = NC > 1 ? (float*)tail : ctxP0;
  float* c2 = NC > 3 ? (float*)(tail + CB) : ctxP0;
  float* c3 = NC > 3 ? (float*)(tail + 2 * CB) : ctxP0;
  int cpb = 32 / NC;                      // q-chunks of cpb*32 rows

  hipMemsetAsync(sums, 0, 32768 * sizeof(float), stream);
  k_wconv<<<dim3(3200), dim3(256), 0, stream>>>(wq, wk, wv, wp, W, WPH, WPL);
  k_xconv<<<dim3(3072), dim3(256), 0, stream>>>(q, k, v, XqH, XqL, XkH, XkL, XvH);
  k_proj <<<dim3(8, 64), dim3(256), 0, stream>>>(XqH, XqL, W, W + NW, bq,
                                                 QsH, QsL, nullptr, 0, 0.5f);
  k_proj <<<dim3(8, 64), dim3(256), 0, stream>>>(XkH, XkL, W + 2 * NW, W + 3 * NW, bk,
                                                 KsH, KsL, nullptr, 0, 1.0f);
  k_proj <<<dim3(8, 64), dim3(256), 0, stream>>>(XvH, XvH, W + 4 * NW, W + 4 * NW, bv,
                                                 nullptr, nullptr, Vt, 1, 1.0f);
  k_sums <<<dim3(16, 32, 4), dim3(256), 0, stream>>>(QsH, KsH, sums);
  k_inv  <<<dim3(128), dim3(256), 0, stream>>>(sums);
  k_pv   <<<dim3(16, 32, NC), dim3(256), 0, stream>>>(QsH, QsL, KsH, KsL, Vt, sums,
                                                      attn, ctxP0, c1, c2, c3, cpb);
  k_red  <<<dim3(1024), dim3(256), 0, stream>>>(ctxP0, c1, c2, c3, NC, ctxH, ctxL);
  k_out  <<<dim3(64), dim3(256), 0, stream>>>(ctxH, ctxL, WPH, WPL, bp, out);
}